// Round 1
// baseline (374.125 us; speedup 1.0000x reference)
//
#include <hip/hip_runtime.h>

#define BB 64
#define TT 16384
#define EE 512

typedef _Float16 half8 __attribute__((ext_vector_type(8)));
typedef float floatx4 __attribute__((ext_vector_type(4)));

static __device__ __forceinline__ half8 cvt_half8(float4 a, float4 b) {
  half8 h;
  h[0] = (_Float16)a.x; h[1] = (_Float16)a.y; h[2] = (_Float16)a.z; h[3] = (_Float16)a.w;
  h[4] = (_Float16)b.x; h[5] = (_Float16)b.y; h[6] = (_Float16)b.z; h[7] = (_Float16)b.w;
  return h;
}

// ---------------------------------------------------------------------------
// Zero the split-K fp32 accumulators. MUST be a kernel (not hipMemsetAsync):
// memset nodes are not reliably captured into the timing graph and d_ws is
// not re-poisoned between replays -> cross-replay accumulation (R1 bug).
// ---------------------------------------------------------------------------
__global__ __launch_bounds__(256) void zero_ws(float4* __restrict__ p) {
  p[blockIdx.x * 256 + threadIdx.x] = (float4){0.f, 0.f, 0.f, 0.f};
}

// ---------------------------------------------------------------------------
// Stage 1 v3: LDS-free, barrier-free streaming GEMM.
// R3 theory: old version was latency-bound (MfmaUtil 5%, HBM 29%, occ 34%) --
// barrier-gated LDS staging burst-stalled all waves each k-tile, and 11.5M
// split-K atomicAdds RMW-serialized at L2. K=16384 >> M,N: every byte is
// used by exactly one fragment, so load MFMA fragments DIRECTLY from global
// (16 rows x 128B contiguous per frag load -> coalesced), cvt in regs, MFMA.
// No barriers in the k-loop -> each wave keeps 12 dwordx4 in flight and the
// compiler pipelines freely.
//   tiles 0..47  : Xq  (3 mtiles x 16 ntiles of 32 cols), rows=(b,3 p)xWq
//   tiles 48..175: Xkv (4 mtiles x 32 ntiles), ntile<16 -> Wk else Wv
// blockIdx.y = outer split-K (8 chunks); the block's 4 waves split the chunk
// (512 k each) and reduce through LDS -> ONE atomicAdd per output element per
// y-chunk: 2.9M atomics total (was 11.5M).
// ---------------------------------------------------------------------------
__global__ __launch_bounds__(256) void proj_gemm(
    const float* __restrict__ x, const float* __restrict__ Wq,
    const float* __restrict__ Wk, const float* __restrict__ Wv,
    float* __restrict__ Xq, float* __restrict__ Xkv)
{
  __shared__ float red[4][2048];   // 32 KB: per-wave partials for 64x32 tile
  const int t = threadIdx.x;
  const int wave = t >> 6, lane = t & 63;
  const int quad = lane >> 4, l16 = lane & 15;

  const int tile = blockIdx.x;
  int mtile, ntile, chan_base, cpb, ldout;
  const float* Wsrc;
  float* outC;
  if (tile < 48) {
    mtile = tile >> 4; ntile = tile & 15;
    chan_base = 0; cpb = 3; ldout = 512;
    Wsrc = Wq; outC = Xq;
  } else {
    const int t2 = tile - 48;
    mtile = t2 >> 5; ntile = t2 & 31;
    chan_base = 3; cpb = 4; ldout = 1024;
    Wsrc = (ntile < 16) ? Wk : Wv; outC = Xkv;
  }
  const int k0 = blockIdx.y * 2048 + wave * 512;   // per-wave K chunk

  // A fragment bases: frag rt covers rows mtile*64+rt*16+l16, k = quad*8..+8
  int aOff[4];
#pragma unroll
  for (int rt = 0; rt < 4; ++rt) {
    const int r = mtile * 64 + rt * 16 + l16;
    const int bidx = r / cpb;
    const int j = r - bidx * cpb;
    aOff[rt] = (bidx * 7 + chan_base + j) * TT + k0 + quad * 8;
  }
  // B fragment bases: frag ct covers weight rows ntile*32+ct*16+l16
  int bOff[2];
#pragma unroll
  for (int ct = 0; ct < 2; ++ct) {
    const int col = (ntile * 32 + ct * 16 + l16) & (EE - 1);
    bOff[ct] = col * TT + k0 + quad * 8;
  }

  floatx4 acc[4][2];
#pragma unroll
  for (int rt = 0; rt < 4; ++rt)
#pragma unroll
    for (int ct = 0; ct < 2; ++ct)
      acc[rt][ct] = (floatx4){0.f, 0.f, 0.f, 0.f};

  // register prefetch buffers (all indices compile-time constant -> VGPRs)
  float4 bufA[4][2], bufB[2][2];
#pragma unroll
  for (int rt = 0; rt < 4; ++rt) {
    bufA[rt][0] = *(const float4*)(x + aOff[rt]);
    bufA[rt][1] = *(const float4*)(x + aOff[rt] + 4);
  }
#pragma unroll
  for (int ct = 0; ct < 2; ++ct) {
    bufB[ct][0] = *(const float4*)(Wsrc + bOff[ct]);
    bufB[ct][1] = *(const float4*)(Wsrc + bOff[ct] + 4);
  }

  for (int kt = 0; kt < 16; ++kt) {
    half8 ha[4], hb[2];
#pragma unroll
    for (int rt = 0; rt < 4; ++rt) ha[rt] = cvt_half8(bufA[rt][0], bufA[rt][1]);
#pragma unroll
    for (int ct = 0; ct < 2; ++ct) hb[ct] = cvt_half8(bufB[ct][0], bufB[ct][1]);
    if (kt < 15) {                 // issue next k-tile's loads NOW
      const int ko = (kt + 1) * 32;
#pragma unroll
      for (int rt = 0; rt < 4; ++rt) {
        bufA[rt][0] = *(const float4*)(x + aOff[rt] + ko);
        bufA[rt][1] = *(const float4*)(x + aOff[rt] + ko + 4);
      }
#pragma unroll
      for (int ct = 0; ct < 2; ++ct) {
        bufB[ct][0] = *(const float4*)(Wsrc + bOff[ct] + ko);
        bufB[ct][1] = *(const float4*)(Wsrc + bOff[ct] + ko + 4);
      }
    }
#pragma unroll
    for (int rt = 0; rt < 4; ++rt) {
      acc[rt][0] = __builtin_amdgcn_mfma_f32_16x16x32_f16(ha[rt], hb[0], acc[rt][0], 0, 0, 0);
      acc[rt][1] = __builtin_amdgcn_mfma_f32_16x16x32_f16(ha[rt], hb[1], acc[rt][1], 0, 0, 0);
    }
  }

  // cross-wave K reduction: C/D layout col=lane&15, row=quad*4+reg
#pragma unroll
  for (int rt = 0; rt < 4; ++rt)
#pragma unroll
    for (int ct = 0; ct < 2; ++ct)
#pragma unroll
      for (int rg = 0; rg < 4; ++rg) {
        const int row = rt * 16 + quad * 4 + rg;
        const int col = ct * 16 + l16;
        red[wave][row * 32 + col] = acc[rt][ct][rg];
      }
  __syncthreads();
  const int base = t * 8;
#pragma unroll
  for (int i = 0; i < 8; ++i) {
    const int idx = base + i;
    const float s = red[0][idx] + red[1][idx] + red[2][idx] + red[3][idx];
    const int row = idx >> 5, col = idx & 31;
    atomicAdd(&outC[(size_t)(mtile * 64 + row) * ldout + ntile * 32 + col], s);
  }
}

// ---------------------------------------------------------------------------
// Stage 2: per (batch, 64-wide e-chunk): build K(16x512), VW(3x512), Q(16x64)
// in LDS, then per e-row: S = 0.25*Q^T K, softmax over f, u[o,e]=P·VW[o]/den.
// (unchanged -- verified correct)
// ---------------------------------------------------------------------------
__global__ __launch_bounds__(256) void attn_mid(
    const float* __restrict__ Xq, const float* __restrict__ Xkv,
    const float* __restrict__ W1, const float* __restrict__ W2,
    const float* __restrict__ W3,
    const float* __restrict__ bq, const float* __restrict__ bk,
    const float* __restrict__ bv, _Float16* __restrict__ U)
{
  __shared__ float Ks[16][512];
  __shared__ float VW[3][512];
  __shared__ float Qs[16][64];
  __shared__ float Xs[4][512];
  __shared__ float W1s[48], W2s[64], W3s[48], W32s[12], w3sum[3];
  const int t = threadIdx.x;
  const int b = blockIdx.y;
  const int e0 = blockIdx.x * 64;

  if (t < 48) W1s[t] = W1[t];
  if (t >= 64 && t < 128) W2s[t - 64] = W2[t - 64];
  if (t >= 128 && t < 176) W3s[t - 128] = W3[t - 128];
  __syncthreads();
  if (t < 12) {                       // W32[o][j] = sum_c W3[o][c]*W2[c][j]
    const int o = t >> 2, jj = t & 3;
    float s = 0.f;
    for (int c = 0; c < 16; ++c) s += W3s[o * 16 + c] * W2s[c * 4 + jj];
    W32s[t] = s;
  }
  if (t >= 16 && t < 19) {
    const int o = t - 16;
    float s = 0.f;
    for (int c = 0; c < 16; ++c) s += W3s[o * 16 + c];
    w3sum[o] = s;
  }
  // stage Xk, build K
  for (int i = t; i < 2048; i += 256) {
    const int jj = i >> 9, f = i & 511;
    Xs[jj][f] = Xkv[(size_t)(b * 4 + jj) * 1024 + f];
  }
  __syncthreads();
  for (int i = t; i < 8192; i += 256) {
    const int c = i >> 9, f = i & 511;
    float s = bk[f];
#pragma unroll
    for (int jj = 0; jj < 4; ++jj) s += W2s[c * 4 + jj] * Xs[jj][f];
    Ks[c][f] = s;
  }
  __syncthreads();
  // stage Xv, build VW
  for (int i = t; i < 2048; i += 256) {
    const int jj = i >> 9, f = i & 511;
    Xs[jj][f] = Xkv[(size_t)(b * 4 + jj) * 1024 + 512 + f];
  }
  __syncthreads();
  for (int i = t; i < 1536; i += 256) {
    const int o = i >> 9, f = i & 511;
    float s = w3sum[o] * bv[f];
#pragma unroll
    for (int jj = 0; jj < 4; ++jj) s += W32s[o * 4 + jj] * Xs[jj][f];
    VW[o][f] = s;
  }
  // build Q for this e-chunk
  for (int i = t; i < 1024; i += 256) {
    const int c = i >> 6, el = i & 63;
    float s = bq[e0 + el];
#pragma unroll
    for (int jj = 0; jj < 3; ++jj)
      s += W1s[c * 3 + jj] * Xq[(size_t)(b * 3 + jj) * 512 + e0 + el];
    Qs[c][el] = s;
  }
  __syncthreads();

  const int wave = t >> 6, lane = t & 63;
  float vwr[3][8];
#pragma unroll
  for (int o = 0; o < 3; ++o) {
    float4 va = *(const float4*)&VW[o][lane * 8];
    float4 vb = *(const float4*)&VW[o][lane * 8 + 4];
    vwr[o][0] = va.x; vwr[o][1] = va.y; vwr[o][2] = va.z; vwr[o][3] = va.w;
    vwr[o][4] = vb.x; vwr[o][5] = vb.y; vwr[o][6] = vb.z; vwr[o][7] = vb.w;
  }

  for (int g = 0; g < 4; ++g) {       // 4 groups of 4 e-rows per wave
    const int el0 = wave * 16 + g * 4;
    float s[4][8];
#pragma unroll
    for (int e = 0; e < 4; ++e)
#pragma unroll
      for (int i = 0; i < 8; ++i) s[e][i] = 0.f;
#pragma unroll
    for (int c = 0; c < 16; ++c) {
      float4 k0 = *(const float4*)&Ks[c][lane * 8];
      float4 k1 = *(const float4*)&Ks[c][lane * 8 + 4];
      float4 qv = *(const float4*)&Qs[c][el0];
      float qa[4] = {qv.x, qv.y, qv.z, qv.w};
#pragma unroll
      for (int e = 0; e < 4; ++e) {
        const float q = qa[e];
        s[e][0] += q * k0.x; s[e][1] += q * k0.y; s[e][2] += q * k0.z; s[e][3] += q * k0.w;
        s[e][4] += q * k1.x; s[e][5] += q * k1.y; s[e][6] += q * k1.z; s[e][7] += q * k1.w;
      }
    }
#pragma unroll
    for (int e = 0; e < 4; ++e) {
      float mx = s[e][0];
#pragma unroll
      for (int i = 1; i < 8; ++i) mx = fmaxf(mx, s[e][i]);
#pragma unroll
      for (int off = 32; off; off >>= 1) mx = fmaxf(mx, __shfl_xor(mx, off));
      float p[8], sum = 0.f;
#pragma unroll
      for (int i = 0; i < 8; ++i) { p[i] = __expf(0.25f * (s[e][i] - mx)); sum += p[i]; }
      float u0 = 0.f, u1 = 0.f, u2 = 0.f;
#pragma unroll
      for (int i = 0; i < 8; ++i) {
        u0 += p[i] * vwr[0][i];
        u1 += p[i] * vwr[1][i];
        u2 += p[i] * vwr[2][i];
      }
#pragma unroll
      for (int off = 32; off; off >>= 1) {
        sum += __shfl_xor(sum, off);
        u0  += __shfl_xor(u0, off);
        u1  += __shfl_xor(u1, off);
        u2  += __shfl_xor(u2, off);
      }
      if (lane == 0) {
        const float inv = 1.0f / sum;
        const size_t base = (size_t)b * 3 * 512 + (e0 + el0 + e);
        U[base]        = (_Float16)(u0 * inv);
        U[base + 512]  = (_Float16)(u1 * inv);
        U[base + 1024] = (_Float16)(u2 * inv);
      }
    }
  }
}

// ---------------------------------------------------------------------------
// Stage 3 v3: LDS-free, barrier-free (same surgery as proj_gemm).
// out[r][t] = sum_e U[r][e]*Wo[t][e] + x[(b*7+o)][t] + w3sum[o]*bo[t]
// r = b*3 + o;  M=192, N=16384, K=512. A=U (fp16, 196KB -> L2 resident)
// loaded as direct half8 fragments; B=Wo rows loaded as direct float8
// fragments (16 rows x 128B contiguous per load). No __syncthreads at all.
// ---------------------------------------------------------------------------
__global__ __launch_bounds__(256) void out_gemm(
    const _Float16* __restrict__ U, const float* __restrict__ Wo,
    const float* __restrict__ x, const float* __restrict__ bo,
    const float* __restrict__ W3, float* __restrict__ outY)
{
  const int t = threadIdx.x;
  const int wave = t >> 6, lane = t & 63;
  const int quad = lane >> 4, l16 = lane & 15;
  const int mtile = blockIdx.y, ntile = blockIdx.x;

  // w3sum per-thread (uniform scalar loads; was __shared__ + barrier)
  float w3s[3];
#pragma unroll
  for (int o = 0; o < 3; ++o) {
    float s = 0.f;
#pragma unroll
    for (int c = 0; c < 16; ++c) s += W3[o * 16 + c];
    w3s[o] = s;
  }

  const int tc = ntile * 64 + wave * 16 + l16;   // this lane's output column
  int aOff[4];
#pragma unroll
  for (int rt = 0; rt < 4; ++rt)
    aOff[rt] = (mtile * 64 + rt * 16 + l16) * EE + quad * 8;
  const int bOff = tc * EE + quad * 8;

  floatx4 acc[4];
#pragma unroll
  for (int rt = 0; rt < 4; ++rt) acc[rt] = (floatx4){0.f, 0.f, 0.f, 0.f};

  half8 bufA[4];
  float4 bufB[2];
#pragma unroll
  for (int rt = 0; rt < 4; ++rt) bufA[rt] = *(const half8*)(U + aOff[rt]);
  bufB[0] = *(const float4*)(Wo + bOff);
  bufB[1] = *(const float4*)(Wo + bOff + 4);

  for (int kt = 0; kt < 16; ++kt) {
    const half8 hb = cvt_half8(bufB[0], bufB[1]);
    half8 ha[4];
#pragma unroll
    for (int rt = 0; rt < 4; ++rt) ha[rt] = bufA[rt];
    if (kt < 15) {
      const int ko = (kt + 1) * 32;
#pragma unroll
      for (int rt = 0; rt < 4; ++rt)
        bufA[rt] = *(const half8*)(U + aOff[rt] + ko);
      bufB[0] = *(const float4*)(Wo + bOff + ko);
      bufB[1] = *(const float4*)(Wo + bOff + ko + 4);
    }
#pragma unroll
    for (int rt = 0; rt < 4; ++rt)
      acc[rt] = __builtin_amdgcn_mfma_f32_16x16x32_f16(ha[rt], hb, acc[rt], 0, 0, 0);
  }

  const float bot = bo[tc];
#pragma unroll
  for (int rt = 0; rt < 4; ++rt) {
    const int gr = mtile * 64 + rt * 16 + quad * 4;
#pragma unroll
    for (int rg = 0; rg < 4; ++rg) {
      const int rr = gr + rg;
      const int bb = rr / 3, oo = rr - bb * 3;
      const float v = acc[rt][rg]
                    + x[(size_t)(bb * 7 + oo) * TT + tc]
                    + w3s[oo] * bot;
      outY[(size_t)rr * TT + tc] = v;
    }
  }
}

extern "C" void kernel_launch(void* const* d_in, const int* in_sizes, int n_in,
                              void* d_out, int out_size, void* d_ws, size_t ws_size,
                              hipStream_t stream) {
  const float* x  = (const float*)d_in[0];
  const float* W1 = (const float*)d_in[1];
  const float* W2 = (const float*)d_in[2];
  const float* Wq = (const float*)d_in[3];
  const float* bq = (const float*)d_in[4];
  const float* Wk = (const float*)d_in[5];
  const float* bk = (const float*)d_in[6];
  const float* Wv = (const float*)d_in[7];
  const float* bv = (const float*)d_in[8];
  const float* Wo = (const float*)d_in[9];
  const float* bo = (const float*)d_in[10];
  const float* W3 = (const float*)d_in[11];
  float* out = (float*)d_out;

  char* ws = (char*)d_ws;
  float* Xq      = (float*)ws;                  // 192*512  fp32 = 393216 B
  float* Xkv     = (float*)(ws + 393216);       // 256*1024 fp32 = 1048576 B
  _Float16* U    = (_Float16*)(ws + 1441792);   // 192*512  fp16 = 196608 B

  // zero the split-K accumulators (kernel, NOT hipMemsetAsync)
  zero_ws<<<dim3(352), 256, 0, stream>>>((float4*)ws);

  // merged projections: 176 MN-tiles x 8 outer split-K chunks = 1408 blocks
  proj_gemm<<<dim3(176, 8), 256, 0, stream>>>(x, Wq, Wk, Wv, Xq, Xkv);
  // attention middle -> U (192 x 512 fp16)
  attn_mid<<<dim3(8, BB), 256, 0, stream>>>(Xq, Xkv, W1, W2, W3, bq, bk, bv, U);
  // final projection + residual + bias
  out_gemm<<<dim3(256, 3), 256, 0, stream>>>(U, Wo, x, bo, W3, out);
}

// Round 3
// 275.233 us; speedup vs baseline: 1.3593x; 1.3593x over previous
//
#include <hip/hip_runtime.h>

#define BB 64
#define TT 16384
#define EE 512

typedef _Float16 half8 __attribute__((ext_vector_type(8)));
typedef float floatx4 __attribute__((ext_vector_type(4)));

static __device__ __forceinline__ half8 cvt_half8(float4 a, float4 b) {
  half8 h;
  h[0] = (_Float16)a.x; h[1] = (_Float16)a.y; h[2] = (_Float16)a.z; h[3] = (_Float16)a.w;
  h[4] = (_Float16)b.x; h[5] = (_Float16)b.y; h[6] = (_Float16)b.z; h[7] = (_Float16)b.w;
  return h;
}

// global -> LDS direct staging, 16B per lane. LDS dest is wave-uniform base +
// lane*16 (hardware); global src is per-lane (this is how the XOR swizzle is
// applied: pre-swizzle the SOURCE, keep LDS linear -- m173 pattern).
static __device__ __forceinline__ void gload_lds16(const void* g, void* l) {
  __builtin_amdgcn_global_load_lds(
      (const __attribute__((address_space(1))) void*)g,
      (__attribute__((address_space(3))) void*)l, 16, 0, 0);
}

// ---------------------------------------------------------------------------
// Zero the split-K fp32 accumulators. MUST be a kernel (not hipMemsetAsync):
// memset nodes are not reliably captured into the timing graph and d_ws is
// not re-poisoned between replays -> cross-replay accumulation (R1 bug).
// ---------------------------------------------------------------------------
__global__ __launch_bounds__(256) void zero_ws(float4* __restrict__ p) {
  p[blockIdx.x * 256 + threadIdx.x] = (float4){0.f, 0.f, 0.f, 0.f};
}

// ---------------------------------------------------------------------------
// Stage 1 v4 (R3 = resubmit of R2; container flake, source audit clean):
// global_load_lds + double-buffer (1 barrier/k-tile) + source-side XOR swizzle.
//   - fp32 staged straight to LDS via global_load_lds dwordx4 (coalesced,
//     no VGPR roundtrip); cvt to fp16 after ds_read, hidden under MFMA.
//   - STAGE(t+1) issued BEFORE compute(t); ONE __syncthreads per k-tile.
//   - LDS [64][32] fp32 linear + source-side XOR swizzle: LDS 16B-unit u of
//     row r holds global unit u^(r&7); ds_read applies same XOR -> content
//     permutation cancels, banks spread 8 lanes/slot = conflict-free.
//   - 64x64 tiles: 88 MN-tiles x 32 k-chunks = 2816 blocks (11/CU, ~5
//     resident at 32KB LDS) -> enough MLP to cover HBM latency.
//   - XCD swizzle: logical = chunk*88 + tile, bijective (2816 = 8*352);
//     each XCD owns 4 whole chunks; per-chunk working set ~= one 4MB L2.
// tiles 0..23: Xq (3m x 8n of 64); 24..87: Xkv (4m x 16n); ntile<8->Wk else Wv
// ---------------------------------------------------------------------------
__global__ __launch_bounds__(256) void proj_gemm(
    const float* __restrict__ x, const float* __restrict__ Wq,
    const float* __restrict__ Wk, const float* __restrict__ Wv,
    float* __restrict__ Xq, float* __restrict__ Xkv)
{
  __shared__ float Abuf[2][64 * 32];   // 8 KB each
  __shared__ float Bbuf[2][64 * 32];   // 8 KB each
  const int t = threadIdx.x;
  const int wave = t >> 6, lane = t & 63;
  const int quad = lane >> 4, l16 = lane & 15;

  const int orig = blockIdx.x;
  const int logical = (orig & 7) * 352 + (orig >> 3);
  const int chunk = logical / 88;            // 0..31, k-chunk of 512
  const int tile  = logical - chunk * 88;
  const int k0 = chunk << 9;

  int mtile, ntile, cpb, chan_base, ldout;
  const float* Wsrc;
  float* outC;
  if (tile < 24) {
    mtile = tile >> 3; ntile = tile & 7;
    cpb = 3; chan_base = 0; ldout = 512;
    Wsrc = Wq + (size_t)(ntile * 64) * TT;
    outC = Xq;
  } else {
    const int t2 = tile - 24;
    mtile = t2 >> 4; ntile = t2 & 15;
    cpb = 4; chan_base = 3; ldout = 1024;
    Wsrc = (ntile < 8) ? (Wk + (size_t)(ntile * 64) * TT)
                       : (Wv + (size_t)((ntile - 8) * 64) * TT);
    outC = Xkv;
  }

  // staging source pointers: tile = 512 16B-units, 2 rounds x 256 threads.
  // round r: unit i = (r*4+wave)*64+lane; row = i>>3; u = i&7;
  // source unit = u ^ (row&7)  (the XOR swizzle, applied on the source side)
  const float* aSrc[2];
  const float* bSrc[2];
#pragma unroll
  for (int r = 0; r < 2; ++r) {
    const int i = (r * 4 + wave) * 64 + lane;
    const int row = i >> 3, u = i & 7;
    const int m = mtile * 64 + row;
    const int bidx = (cpb == 3) ? ((m * 21846) >> 16) : (m >> 2);
    const int j = m - bidx * cpb;
    const int swu = (u ^ (row & 7)) << 2;
    aSrc[r] = x + (size_t)(bidx * 7 + chan_base + j) * TT + k0 + swu;
    bSrc[r] = Wsrc + (size_t)row * TT + k0 + swu;
  }

  floatx4 acc[4];
#pragma unroll
  for (int rt = 0; rt < 4; ++rt) acc[rt] = (floatx4){0.f, 0.f, 0.f, 0.f};

  // prologue: stage k-tile 0 into buf 0
#pragma unroll
  for (int r = 0; r < 2; ++r) {
    gload_lds16(aSrc[r], &Abuf[0][(r * 4 + wave) * 256]);
    gload_lds16(bSrc[r], &Bbuf[0][(r * 4 + wave) * 256]);
  }
  __syncthreads();   // drains vmcnt(0): tile 0 resident

  int cur = 0;
  const int brow = wave * 16 + l16;    // this lane's B-tile row (output col)
  const int bsw = brow & 7;
  for (int kt = 0; kt < 16; ++kt) {
    if (kt < 15) {                     // issue next tile's stage FIRST
      const int ko = (kt + 1) * 32;
      const int nxt = cur ^ 1;
#pragma unroll
      for (int r = 0; r < 2; ++r) {
        gload_lds16(aSrc[r] + ko, &Abuf[nxt][(r * 4 + wave) * 256]);
        gload_lds16(bSrc[r] + ko, &Bbuf[nxt][(r * 4 + wave) * 256]);
      }
    }
    // B fragment: rows wave*16+l16, k = quad*8..+8 (swizzled read)
    float4 b0 = *(const float4*)&Bbuf[cur][brow * 32 + ((((quad << 1) | 0) ^ bsw) << 2)];
    float4 b1 = *(const float4*)&Bbuf[cur][brow * 32 + ((((quad << 1) | 1) ^ bsw) << 2)];
    const half8 hb = cvt_half8(b0, b1);
#pragma unroll
    for (int rt = 0; rt < 4; ++rt) {
      const int arow = rt * 16 + l16;
      const int asw = arow & 7;
      float4 a0 = *(const float4*)&Abuf[cur][arow * 32 + ((((quad << 1) | 0) ^ asw) << 2)];
      float4 a1 = *(const float4*)&Abuf[cur][arow * 32 + ((((quad << 1) | 1) ^ asw) << 2)];
      acc[rt] = __builtin_amdgcn_mfma_f32_16x16x32_f16(cvt_half8(a0, a1), hb, acc[rt], 0, 0, 0);
    }
    if (kt < 15) {
      __syncthreads();                 // one barrier per k-tile (drains vmcnt)
      cur ^= 1;
    }
  }

  // epilogue: C/D layout col=lane&15, row=quad*4+reg
  const int gc = ntile * 64 + wave * 16 + l16;
#pragma unroll
  for (int rt = 0; rt < 4; ++rt) {
    const int gr = mtile * 64 + rt * 16 + quad * 4;
#pragma unroll
    for (int rg = 0; rg < 4; ++rg)
      atomicAdd(&outC[(size_t)(gr + rg) * ldout + gc], acc[rt][rg]);
  }
}

// ---------------------------------------------------------------------------
// Stage 2: per (batch, 64-wide e-chunk): build K(16x512), VW(3x512), Q(16x64)
// in LDS, then per e-row: S = 0.25*Q^T K, softmax over f, u[o,e]=P·VW[o]/den.
// (unchanged -- verified correct)
// ---------------------------------------------------------------------------
__global__ __launch_bounds__(256) void attn_mid(
    const float* __restrict__ Xq, const float* __restrict__ Xkv,
    const float* __restrict__ W1, const float* __restrict__ W2,
    const float* __restrict__ W3,
    const float* __restrict__ bq, const float* __restrict__ bk,
    const float* __restrict__ bv, _Float16* __restrict__ U)
{
  __shared__ float Ks[16][512];
  __shared__ float VW[3][512];
  __shared__ float Qs[16][64];
  __shared__ float Xs[4][512];
  __shared__ float W1s[48], W2s[64], W3s[48], W32s[12], w3sum[3];
  const int t = threadIdx.x;
  const int b = blockIdx.y;
  const int e0 = blockIdx.x * 64;

  if (t < 48) W1s[t] = W1[t];
  if (t >= 64 && t < 128) W2s[t - 64] = W2[t - 64];
  if (t >= 128 && t < 176) W3s[t - 128] = W3[t - 128];
  __syncthreads();
  if (t < 12) {                       // W32[o][j] = sum_c W3[o][c]*W2[c][j]
    const int o = t >> 2, jj = t & 3;
    float s = 0.f;
    for (int c = 0; c < 16; ++c) s += W3s[o * 16 + c] * W2s[c * 4 + jj];
    W32s[t] = s;
  }
  if (t >= 16 && t < 19) {
    const int o = t - 16;
    float s = 0.f;
    for (int c = 0; c < 16; ++c) s += W3s[o * 16 + c];
    w3sum[o] = s;
  }
  // stage Xk, build K
  for (int i = t; i < 2048; i += 256) {
    const int jj = i >> 9, f = i & 511;
    Xs[jj][f] = Xkv[(size_t)(b * 4 + jj) * 1024 + f];
  }
  __syncthreads();
  for (int i = t; i < 8192; i += 256) {
    const int c = i >> 9, f = i & 511;
    float s = bk[f];
#pragma unroll
    for (int jj = 0; jj < 4; ++jj) s += W2s[c * 4 + jj] * Xs[jj][f];
    Ks[c][f] = s;
  }
  __syncthreads();
  // stage Xv, build VW
  for (int i = t; i < 2048; i += 256) {
    const int jj = i >> 9, f = i & 511;
    Xs[jj][f] = Xkv[(size_t)(b * 4 + jj) * 1024 + 512 + f];
  }
  __syncthreads();
  for (int i = t; i < 1536; i += 256) {
    const int o = i >> 9, f = i & 511;
    float s = w3sum[o] * bv[f];
#pragma unroll
    for (int jj = 0; jj < 4; ++jj) s += W32s[o * 4 + jj] * Xs[jj][f];
    VW[o][f] = s;
  }
  // build Q for this e-chunk
  for (int i = t; i < 1024; i += 256) {
    const int c = i >> 6, el = i & 63;
    float s = bq[e0 + el];
#pragma unroll
    for (int jj = 0; jj < 3; ++jj)
      s += W1s[c * 3 + jj] * Xq[(size_t)(b * 3 + jj) * 512 + e0 + el];
    Qs[c][el] = s;
  }
  __syncthreads();

  const int wave = t >> 6, lane = t & 63;
  float vwr[3][8];
#pragma unroll
  for (int o = 0; o < 3; ++o) {
    float4 va = *(const float4*)&VW[o][lane * 8];
    float4 vb = *(const float4*)&VW[o][lane * 8 + 4];
    vwr[o][0] = va.x; vwr[o][1] = va.y; vwr[o][2] = va.z; vwr[o][3] = va.w;
    vwr[o][4] = vb.x; vwr[o][5] = vb.y; vwr[o][6] = vb.z; vwr[o][7] = vb.w;
  }

  for (int g = 0; g < 4; ++g) {       // 4 groups of 4 e-rows per wave
    const int el0 = wave * 16 + g * 4;
    float s[4][8];
#pragma unroll
    for (int e = 0; e < 4; ++e)
#pragma unroll
      for (int i = 0; i < 8; ++i) s[e][i] = 0.f;
#pragma unroll
    for (int c = 0; c < 16; ++c) {
      float4 k0 = *(const float4*)&Ks[c][lane * 8];
      float4 k1 = *(const float4*)&Ks[c][lane * 8 + 4];
      float4 qv = *(const float4*)&Qs[c][el0];
      float qa[4] = {qv.x, qv.y, qv.z, qv.w};
#pragma unroll
      for (int e = 0; e < 4; ++e) {
        const float q = qa[e];
        s[e][0] += q * k0.x; s[e][1] += q * k0.y; s[e][2] += q * k0.z; s[e][3] += q * k0.w;
        s[e][4] += q * k1.x; s[e][5] += q * k1.y; s[e][6] += q * k1.z; s[e][7] += q * k1.w;
      }
    }
#pragma unroll
    for (int e = 0; e < 4; ++e) {
      float mx = s[e][0];
#pragma unroll
      for (int i = 1; i < 8; ++i) mx = fmaxf(mx, s[e][i]);
#pragma unroll
      for (int off = 32; off; off >>= 1) mx = fmaxf(mx, __shfl_xor(mx, off));
      float p[8], sum = 0.f;
#pragma unroll
      for (int i = 0; i < 8; ++i) { p[i] = __expf(0.25f * (s[e][i] - mx)); sum += p[i]; }
      float u0 = 0.f, u1 = 0.f, u2 = 0.f;
#pragma unroll
      for (int i = 0; i < 8; ++i) {
        u0 += p[i] * vwr[0][i];
        u1 += p[i] * vwr[1][i];
        u2 += p[i] * vwr[2][i];
      }
#pragma unroll
      for (int off = 32; off; off >>= 1) {
        sum += __shfl_xor(sum, off);
        u0  += __shfl_xor(u0, off);
        u1  += __shfl_xor(u1, off);
        u2  += __shfl_xor(u2, off);
      }
      if (lane == 0) {
        const float inv = 1.0f / sum;
        const size_t base = (size_t)b * 3 * 512 + (e0 + el0 + e);
        U[base]        = (_Float16)(u0 * inv);
        U[base + 512]  = (_Float16)(u1 * inv);
        U[base + 1024] = (_Float16)(u2 * inv);
      }
    }
  }
}

// ---------------------------------------------------------------------------
// Stage 3 v4: same template as proj_gemm (global_load_lds + dbuf + swizzle).
// out[r][t] = sum_e U[r][e]*Wo[t][e] + x[(b*7+o)][t] + w3sum[o]*bo[t]
// M=192, N=16384, K=512. A=U fp16 [64][32] (4KB, 1 stage instr/thread,
// swizzle u^=(row&3), 4 units/row); B=Wo fp32 [64][32] (8KB, as proj).
// 24KB dbuf -> 6 blocks/CU. 768 blocks, no split-K (K=512 done in-block).
// ---------------------------------------------------------------------------
__global__ __launch_bounds__(256) void out_gemm(
    const _Float16* __restrict__ U, const float* __restrict__ Wo,
    const float* __restrict__ x, const float* __restrict__ bo,
    const float* __restrict__ W3, float* __restrict__ outY)
{
  __shared__ _Float16 Au[2][64 * 32];  // 4 KB each
  __shared__ float    Bw[2][64 * 32];  // 8 KB each
  const int t = threadIdx.x;
  const int wave = t >> 6, lane = t & 63;
  const int quad = lane >> 4, l16 = lane & 15;
  const int mtile = blockIdx.y, ntile = blockIdx.x;

  float w3s[3];
#pragma unroll
  for (int o = 0; o < 3; ++o) {
    float s = 0.f;
#pragma unroll
    for (int c = 0; c < 16; ++c) s += W3[o * 16 + c];
    w3s[o] = s;
  }

  // A staging: 256 units of 16B (8 halfs); unit i = wave*64+lane;
  // row = i>>2, u = i&3; src unit = u ^ (row&3)
  const int ai = wave * 64 + lane;
  const int arow_s = ai >> 2, au = ai & 3;
  const _Float16* aSrc = U + (size_t)(mtile * 64 + arow_s) * EE
                           + ((au ^ (arow_s & 3)) << 3);
  // B staging: 512 units, 2 rounds; row = i>>3, u = i&7; src unit = u^(row&7)
  const float* bSrc[2];
#pragma unroll
  for (int r = 0; r < 2; ++r) {
    const int i = (r * 4 + wave) * 64 + lane;
    const int row = i >> 3, u = i & 7;
    bSrc[r] = Wo + (size_t)(ntile * 64 + row) * EE + ((u ^ (row & 7)) << 2);
  }

  floatx4 acc[4];
#pragma unroll
  for (int rt = 0; rt < 4; ++rt) acc[rt] = (floatx4){0.f, 0.f, 0.f, 0.f};

  // prologue: stage k-tile 0
  gload_lds16(aSrc, &Au[0][wave * 512]);
#pragma unroll
  for (int r = 0; r < 2; ++r)
    gload_lds16(bSrc[r], &Bw[0][(r * 4 + wave) * 256]);
  __syncthreads();

  int cur = 0;
  const int brow = wave * 16 + l16;
  const int bsw = brow & 7;
  for (int kt = 0; kt < 16; ++kt) {
    if (kt < 15) {
      const int nxt = cur ^ 1;
      gload_lds16(aSrc + (kt + 1) * 32, &Au[nxt][wave * 512]);
#pragma unroll
      for (int r = 0; r < 2; ++r)
        gload_lds16(bSrc[r] + (kt + 1) * 32, &Bw[nxt][(r * 4 + wave) * 256]);
    }
    float4 b0 = *(const float4*)&Bw[cur][brow * 32 + ((((quad << 1) | 0) ^ bsw) << 2)];
    float4 b1 = *(const float4*)&Bw[cur][brow * 32 + ((((quad << 1) | 1) ^ bsw) << 2)];
    const half8 hb = cvt_half8(b0, b1);
#pragma unroll
    for (int rt = 0; rt < 4; ++rt) {
      const int arow = rt * 16 + l16;
      const half8 ha = *(const half8*)&Au[cur][arow * 32 + ((quad ^ (arow & 3)) << 3)];
      acc[rt] = __builtin_amdgcn_mfma_f32_16x16x32_f16(ha, hb, acc[rt], 0, 0, 0);
    }
    if (kt < 15) {
      __syncthreads();
      cur ^= 1;
    }
  }

  const int tc = ntile * 64 + wave * 16 + l16;
  const float bot = bo[tc];
#pragma unroll
  for (int rt = 0; rt < 4; ++rt) {
    const int gr = mtile * 64 + rt * 16 + quad * 4;
#pragma unroll
    for (int rg = 0; rg < 4; ++rg) {
      const int rr = gr + rg;
      const int bb = rr / 3, oo = rr - bb * 3;
      const float v = acc[rt][rg]
                    + x[(size_t)(bb * 7 + oo) * TT + tc]
                    + w3s[oo] * bot;
      outY[(size_t)rr * TT + tc] = v;
    }
  }
}

extern "C" void kernel_launch(void* const* d_in, const int* in_sizes, int n_in,
                              void* d_out, int out_size, void* d_ws, size_t ws_size,
                              hipStream_t stream) {
  const float* x  = (const float*)d_in[0];
  const float* W1 = (const float*)d_in[1];
  const float* W2 = (const float*)d_in[2];
  const float* Wq = (const float*)d_in[3];
  const float* bq = (const float*)d_in[4];
  const float* Wk = (const float*)d_in[5];
  const float* bk = (const float*)d_in[6];
  const float* Wv = (const float*)d_in[7];
  const float* bv = (const float*)d_in[8];
  const float* Wo = (const float*)d_in[9];
  const float* bo = (const float*)d_in[10];
  const float* W3 = (const float*)d_in[11];
  float* out = (float*)d_out;

  char* ws = (char*)d_ws;
  float* Xq      = (float*)ws;                  // 192*512  fp32 = 393216 B
  float* Xkv     = (float*)(ws + 393216);       // 256*1024 fp32 = 1048576 B
  _Float16* U    = (_Float16*)(ws + 1441792);   // 192*512  fp16 = 196608 B

  // zero the split-K accumulators (kernel, NOT hipMemsetAsync)
  zero_ws<<<dim3(352), 256, 0, stream>>>((float4*)ws);

  // merged projections: 88 MN-tiles x 32 k-chunks = 2816 blocks
  proj_gemm<<<dim3(2816), 256, 0, stream>>>(x, Wq, Wk, Wv, Xq, Xkv);
  // attention middle -> U (192 x 512 fp16)
  attn_mid<<<dim3(8, BB), 256, 0, stream>>>(Xq, Xkv, W1, W2, W3, bq, bk, bv, U);
  // final projection + residual + bias
  out_gemm<<<dim3(256, 3), 256, 0, stream>>>(U, Wo, x, bo, W3, out);
}